// Round 7
// baseline (444.680 us; speedup 1.0000x reference)
//
#include <hip/hip_runtime.h>

// Problem constants (fixed by reference)
#define CI    16
#define CO    16
#define TAPS  9      // 3x3
#define HID   256
#define KPAD  288    // 256 + 32; k==256 row carries b2, k>256 zero
#define NKK   9      // KPAD/32 MFMA K-steps
#define NCH   144    // CI*TAPS columns per output channel
#define IMGH  128
#define IMGW  128

typedef float  f32x4  __attribute__((ext_vector_type(4)));
typedef float  f32x4v __attribute__((ext_vector_type(4)));
typedef short  bf16x8 __attribute__((ext_vector_type(8)));

__device__ __host__ __forceinline__ short f2bf(float f) {
  union { float f; unsigned u; } c; c.f = f;
  unsigned b = c.u + 0x7FFFu + ((c.u >> 16) & 1u);   // RNE
  return (short)(b >> 16);
}

// ---------------------------------------------------------------------------
// Prep: W2 [256][2304] fp32 (+ b2[2304]) -> W2b [o][kk][n:144][k:32] bf16,
// K padded to 288 (row 256 = b2, rows 257..287 = 0).
// ---------------------------------------------------------------------------
__global__ void prep_w2(const float* __restrict__ W2, const float* __restrict__ b2,
                        short* __restrict__ W2b) {
  __shared__ float tile[32][65];
  const int kk = blockIdx.x % NKK;
  const int colbase = (blockIdx.x / NKK) * 64;
  const int tid = threadIdx.x;

  for (int e = tid; e < 2048; e += 256) {
    int klr = e >> 6;          // 0..31
    int cc  = e & 63;
    int col = colbase + cc;
    float v;
    if (kk < 8) v = W2[(kk * 32 + klr) * (CO * NCH) + col];
    else        v = (klr == 0) ? b2[col] : 0.f;
    tile[klr][cc] = v;
  }
  __syncthreads();
  for (int e = tid; e < 2048; e += 256) {
    int cc = e >> 5;           // 0..63
    int kl = e & 31;
    int col = colbase + cc;
    int o = col / NCH;
    int n = col - o * NCH;
    W2b[(((o * NKK + kk) * NCH + n) << 5) + kl] = f2bf(tile[kl][cc]);
  }
}

// ---------------------------------------------------------------------------
// v7 redesign: wave w owns pixels [w*16, w*16+16) and loops over ALL 16
// output channels. A-fragments (16 pixels x K=288) live permanently in 36
// VGPRs -- shH is GONE (no LDS H tile, no A-side ds_reads, no H barriers).
// Live set ~110 regs < the 128 the allocator pins (R1-R6: VGPR_Count==128
// invariant, structural scratch spill) -> spill impossible by construction.
// LDS = slab (24.4 KB) + out-tile (4 KB) -> 4 blocks/CU = 16 waves (2x occ).
// All 4 waves stream the SAME B frags; per-(o,kk) barrier keeps them in a
// 9 KiB window so L1/MSHR dedupes -> ~1x L2 traffic on W2b.
// grid = 4 batches * 128 rows * 2 half-rows = 1024 blocks x 256 threads.
// ---------------------------------------------------------------------------
__global__ __launch_bounds__(256, 4)
void ngconv_main(const float* __restrict__ in, const float* __restrict__ foa,
                 const float* __restrict__ W1, const float* __restrict__ b1,
                 const short* __restrict__ W2b, float* __restrict__ out) {
  __shared__ float shSlab[CI * 3 * 130];     // reflect-padded input slab, 24.4 KB
  __shared__ float shOut[CO][64];            // output staging, 4 KB

  const int tid  = threadIdx.x;
  const int lane = tid & 63;
  const int wv   = tid >> 6;
  const int c15  = lane & 15;
  const int quad = lane >> 4;

  const int blk = blockIdx.x;
  const int b   = blk >> 8;
  const int rem = blk & 255;
  const int y   = rem >> 1;
  const int x0  = (rem & 1) << 6;

  const float fx  = foa[b * 2 + 0];
  const float fy  = foa[b * 2 + 1];
  const float dyv = (float)y - fy;

  const int ry0 = (y == 0) ? 1 : (y - 1);
  const int ry2 = (y == IMGH - 1) ? (IMGH - 2) : (y + 1);

  // ---- input slab: 16 ch x 3 rows x [1..128], cols 0/129 are x-reflections
  for (int e = tid; e < CI * 3 * IMGW; e += 256) {
    int xs = e & 127;
    int rowid = e >> 7;                 // 0..47
    int i = rowid / 3, r = rowid - (rowid / 3) * 3;
    int ryr = (r == 0) ? ry0 : ((r == 1) ? y : ry2);
    shSlab[(i * 3 + r) * 130 + 1 + xs] =
        in[((b * CI + i) * IMGH + ryr) * IMGW + xs];
  }
  if (tid < CI * 3) {
    int i = tid / 3, r = tid - (tid / 3) * 3;
    int ryr = (r == 0) ? ry0 : ((r == 1) ? y : ry2);
    const float* src = &in[((b * CI + i) * IMGH + ryr) * IMGW];
    shSlab[(i * 3 + r) * 130 + 0]   = src[1];     // reflect(x=-1) -> 1
    shSlab[(i * 3 + r) * 130 + 129] = src[126];   // reflect(x=128) -> 126
  }

  // ---- A fragments in registers: lane (c15,quad) holds H[pixel=c15 of this
  // wave's 16][k = kk*32 + quad*8 + j].  h = relu(dx*W1[0,k]+dy*W1[1,k]+b1[k])
  const float dxv = (float)(x0 + wv * 16 + c15) - fx;
  bf16x8 af[9];
  #pragma unroll
  for (int kk = 0; kk < 8; ++kk) {
    short hv[8];
    #pragma unroll
    for (int j = 0; j < 8; ++j) {
      int k = kk * 32 + quad * 8 + j;
      float h = fmaxf(fmaf(dxv, W1[k], fmaf(dyv, W1[HID + k], b1[k])), 0.f);
      hv[j] = f2bf(h);
    }
    af[kk] = *(bf16x8*)hv;
  }
  {
    short hv[8];
    #pragma unroll
    for (int j = 0; j < 8; ++j) hv[j] = 0;
    if (quad == 0) hv[0] = f2bf(1.f);   // k==256 row = 1 (bias b2)
    af[8] = *(bf16x8*)hv;
  }

  // ---- per-lane patch LDS offsets (pixel = x0 + wv*16 + quad*4 + r)
  int poff[9];
  #pragma unroll
  for (int nt = 0; nt < 9; ++nt) {
    int n15 = nt * 16 + c15;          // 0..143
    int i = n15 / 9;
    int q = n15 - i * 9;              // tap: dyr = q/3, dx = q%3
    int dyr = q / 3;
    poff[nt] = (i * 3 + dyr) * 130 + (q - dyr * 3) + x0 + wv * 16 + quad * 4;
  }

  __syncthreads();

  // per-lane B base; frag f = (o*9+kk)*9+nt lives at Bb + f*512 (shorts)
  const short* Bb = W2b + (c15 << 5) + (quad << 3);

  // ---- main loop over the 16 output channels
  #pragma unroll 1
  for (int o = 0; o < 16; ++o) {
    f32x4 acc[9];
    #pragma unroll
    for (int nt = 0; nt < 9; ++nt) acc[nt] = (f32x4){0.f, 0.f, 0.f, 0.f};

    #pragma unroll 1
    for (int kk = 0; kk < NKK; ++kk) {
      __syncthreads();   // keep 4 waves' identical B streams in one 9KiB window
      const short* Bo = Bb + ((size_t)(o * 81 + kk * 9) << 9);
      #pragma unroll
      for (int batch = 0; batch < 3; ++batch) {
        bf16x8 bfr[3];
        #pragma unroll
        for (int j = 0; j < 3; ++j)
          bfr[j] = *(const bf16x8*)&Bo[(size_t)(batch * 3 + j) << 9];
        #pragma unroll
        for (int j = 0; j < 3; ++j)
          acc[batch * 3 + j] = __builtin_amdgcn_mfma_f32_16x16x32_bf16(
              af[kk], bfr[j], acc[batch * 3 + j], 0, 0, 0);
      }
    }

    // ---- epilogue: contract with patches; C layout: pixel=quad*4+r, n-col=c15
    float P[4] = {0.f, 0.f, 0.f, 0.f};
    #pragma unroll
    for (int nt = 0; nt < 9; ++nt)
      #pragma unroll
      for (int r = 0; r < 4; ++r)
        P[r] = fmaf(acc[nt][r], shSlab[poff[nt] + r], P[r]);

    // reduce over the 16-lane column group, scattering r over c15 bits 3..2
    {
      bool hi = (c15 & 8) != 0;
      float k0 = hi ? P[2] : P[0], s0 = hi ? P[0] : P[2];
      float k1 = hi ? P[3] : P[1], s1 = hi ? P[1] : P[3];
      P[0] = k0 + __shfl_xor(s0, 8, 64);
      P[1] = k1 + __shfl_xor(s1, 8, 64);
    }
    {
      bool hi = (c15 & 4) != 0;
      float k0 = hi ? P[1] : P[0], s0 = hi ? P[0] : P[1];
      P[0] = k0 + __shfl_xor(s0, 4, 64);
    }
    P[0] += __shfl_xor(P[0], 2, 64);
    P[0] += __shfl_xor(P[0], 1, 64);

    if ((c15 & 3) == 0)
      shOut[o][wv * 16 + quad * 4 + (c15 >> 2)] = P[0];
  }

  __syncthreads();
  // ---- coalesced flush: 16 threads per channel row, float4 each
  {
    int o  = tid >> 4;
    int xg = (tid & 15) << 2;
    f32x4v v = *(const f32x4v*)&shOut[o][xg];
    *(f32x4v*)&out[((b * CO + o) * IMGH + y) * IMGW + x0 + xg] = v;
  }
}

// ---------------------------------------------------------------------------
extern "C" void kernel_launch(void* const* d_in, const int* in_sizes, int n_in,
                              void* d_out, int out_size, void* d_ws, size_t ws_size,
                              hipStream_t stream) {
  const float* in  = (const float*)d_in[0];   // [4,16,128,128]
  const float* foa = (const float*)d_in[1];   // [4,2]
  const float* W1  = (const float*)d_in[2];   // [2,256]
  const float* b1  = (const float*)d_in[3];   // [256]
  const float* W2  = (const float*)d_in[4];   // [256,2304]
  const float* b2  = (const float*)d_in[5];   // [2304]
  float* out = (float*)d_out;
  short* W2b = (short*)d_ws;                  // 16*9*144*32 bf16 = 1.33 MB

  prep_w2<<<324, 256, 0, stream>>>(W2, b2, W2b);
  ngconv_main<<<1024, 256, 0, stream>>>(in, foa, W1, b1, W2b, out);
}

// Round 8
// 239.211 us; speedup vs baseline: 1.8589x; 1.8589x over previous
//
#include <hip/hip_runtime.h>

// Problem constants (fixed by reference)
#define CI    16
#define CO    16
#define HID   256
#define NKK   8      // K=256, 8 MFMA K-steps of 32 (b2 folded into epilogue)
#define NCH   144    // CI*9 columns per output channel
#define IMGH  128
#define IMGW  128
#define PS    148    // shPatch row stride in floats (px-major), 2-way-free reads
#define OSTR  36864  // W2b shorts per o: 8 kk * 144 n * 32 k

typedef float f32x4  __attribute__((ext_vector_type(4)));
typedef short bf16x8 __attribute__((ext_vector_type(8)));

__device__ __host__ __forceinline__ short f2bf(float f) {
  union { float f; unsigned u; } c; c.f = f;
  unsigned b = c.u + 0x7FFFu + ((c.u >> 16) & 1u);   // RNE
  return (short)(b >> 16);
}

// ---------------------------------------------------------------------------
// Prep: W2 [256][2304] fp32 -> W2b [o][kk:8][n:144][k:32] bf16 (K=256, no pad)
// grid = 36 col-blocks * 8 kk = 288 blocks x 256 threads.
// ---------------------------------------------------------------------------
__global__ void prep_w2(const float* __restrict__ W2, short* __restrict__ W2b) {
  __shared__ float tile[32][65];
  const int kk = blockIdx.x & 7;
  const int colbase = (blockIdx.x >> 3) * 64;
  const int tid = threadIdx.x;

  for (int e = tid; e < 2048; e += 256) {
    int klr = e >> 6;          // 0..31
    int cc  = e & 63;
    tile[klr][cc] = W2[(kk * 32 + klr) * (CO * NCH) + colbase + cc];
  }
  __syncthreads();
  for (int e = tid; e < 2048; e += 256) {
    int cc = e >> 5;           // 0..63
    int kl = e & 31;
    int col = colbase + cc;
    int o = col / NCH;
    int n = col - o * NCH;
    W2b[(((o * NKK + kk) * NCH + n) << 5) + kl] = f2bf(tile[kl][cc]);
  }
}

// ---------------------------------------------------------------------------
// Main fused kernel, v8. One block = 64 consecutive pixels of one image row.
// 4 waves; wave w computes channels {w, w+4, w+8, w+12}; M=64 per wave via
// acc[4 m-tiles][3 n-tiles] passes (B frag register-reuse = 4).
// - shHf: H tile pre-arranged in MFMA FRAGMENT ORDER -> A ds_read_b128 is
//   lane*16B sequential = conflict-free by construction.
// - shPatch[px][n] (stride 148): epilogue reads exact 2-way = free.
// - K=256; b2 folded into epilogue: P += (acc + b2[col]) * patch.
// - per-pass epilogue: only 1 reg (oacc) crosses pass boundaries -> no spill.
// grid = 4 batches * 128 rows * 2 half-rows = 1024 blocks x 256 threads.
// ---------------------------------------------------------------------------
__global__ __launch_bounds__(256, 2)
void ngconv_main(const float* __restrict__ in, const float* __restrict__ foa,
                 const float* __restrict__ W1, const float* __restrict__ b1,
                 const short* __restrict__ W2b, const float* __restrict__ b2,
                 float* __restrict__ out) {
  __shared__ short shHf[32 * 512];        // 32 frags (ms,kk) x 1 KiB = 32 KB
  __shared__ float shPatch[64 * PS];      // patch matrix, 37 KB

  const int tid  = threadIdx.x;
  const int lane = tid & 63;
  const int wv   = tid >> 6;
  const int c15  = lane & 15;
  const int quad = lane >> 4;

  const int blk = blockIdx.x;
  const int b   = blk >> 8;
  const int rem = blk & 255;
  const int y   = rem >> 1;
  const int x0  = (rem & 1) << 6;

  const float fx  = foa[b * 2 + 0];
  const float fy  = foa[b * 2 + 1];
  const float dyv = (float)y - fy;

  const int ry0 = (y == 0) ? 1 : (y - 1);
  const int ry2 = (y == IMGH - 1) ? (IMGH - 2) : (y + 1);

  // ---- shPatch[px][n]: patch value for pixel px (block-local), column n
  for (int e = tid; e < NCH * 64; e += 256) {
    int n  = e >> 6;                  // 0..143
    int px = e & 63;
    int i = n / 9, q = n - i * 9;
    int dyr = q / 3, dx = q - dyr * 3;
    int ryr = (dyr == 0) ? ry0 : ((dyr == 1) ? y : ry2);
    int x = x0 + px + dx - 1;
    x = (x < 0) ? 1 : ((x > IMGW - 1) ? (IMGW - 2) : x);   // reflect
    shPatch[px * PS + n] = in[((b * CI + i) * IMGH + ryr) * IMGW + x];
  }

  // ---- shHf: H in fragment order. frag(ms,kk) holds A[16 px][32 k]:
  // lane (c15,quad) slot = px=c15, k=kk*32+quad*8..+7 at frag*512 + lane*8.
  for (int g = tid; g < 64 * 32; g += 256) {
    int px = g & 63;                  // pixel (coalesced-ish writes)
    int ks = g >> 6;                  // k-slot 0..31 -> k0 = ks*8
    int k0 = ks << 3;
    float dxv = (float)(x0 + px) - fx;
    short hv[8];
    #pragma unroll
    for (int j = 0; j < 8; ++j) {
      int k = k0 + j;
      float h = fmaxf(fmaf(dxv, W1[k], fmaf(dyv, W1[HID + k], b1[k])), 0.f);
      hv[j] = f2bf(h);
    }
    int ms   = px >> 4;
    int kk   = k0 >> 5;
    int lslot = ((k0 & 31) >> 3) * 16 + (px & 15);   // quad*16 + c15
    *(bf16x8*)&shHf[((ms * NKK + kk) << 9) + (lslot << 3)] = *(bf16x8*)hv;
  }
  __syncthreads();

  // ---- main loop: 4 output channels per wave, N in three passes of 3
  #pragma unroll 1
  for (int oj = 0; oj < 4; ++oj) {
    const int o = wv + oj * 4;
    const short* Bo = W2b + o * OSTR + (c15 << 5) + (quad << 3);
    float oacc = 0.f;

    #pragma unroll 1
    for (int pass = 0; pass < 3; ++pass) {
      const int nb = pass * 3;        // first n-tile of this pass
      f32x4 acc[4][3];
      #pragma unroll
      for (int ms = 0; ms < 4; ++ms)
        #pragma unroll
        for (int j = 0; j < 3; ++j)
          acc[ms][j] = (f32x4){0.f, 0.f, 0.f, 0.f};

      // ping-pong B prefetch, distance 1 (bounded live window, no spill)
      bf16x8 bcur[3];
      #pragma unroll
      for (int j = 0; j < 3; ++j)
        bcur[j] = *(const bf16x8*)&Bo[((nb + j) << 9)];

      #pragma unroll 1
      for (int kk = 0; kk < NKK; ++kk) {
        bf16x8 bnxt[3];
        const int kkn = (kk < NKK - 1) ? (kk + 1) : kk;
        #pragma unroll
        for (int j = 0; j < 3; ++j)
          bnxt[j] = *(const bf16x8*)&Bo[kkn * (NCH * 32) + ((nb + j) << 9)];
        #pragma unroll
        for (int ms = 0; ms < 4; ++ms) {
          bf16x8 af = *(const bf16x8*)&shHf[((ms * NKK + kk) << 9) + (lane << 3)];
          #pragma unroll
          for (int j = 0; j < 3; ++j)
            acc[ms][j] = __builtin_amdgcn_mfma_f32_16x16x32_bf16(
                af, bcur[j], acc[ms][j], 0, 0, 0);
        }
        #pragma unroll
        for (int j = 0; j < 3; ++j) bcur[j] = bnxt[j];
      }

      // ---- per-pass epilogue: P += (acc + b2[col]) * patch
      float b2v[3];
      #pragma unroll
      for (int j = 0; j < 3; ++j)
        b2v[j] = b2[o * NCH + ((nb + j) << 4) + c15];

      float P[16];
      #pragma unroll
      for (int t = 0; t < 16; ++t) P[t] = 0.f;
      #pragma unroll
      for (int j = 0; j < 3; ++j) {
        int n15 = ((nb + j) << 4) + c15;
        #pragma unroll
        for (int ms = 0; ms < 4; ++ms) {
          int pxb = (ms * 16 + quad * 4) * PS + n15;
          #pragma unroll
          for (int r = 0; r < 4; ++r)
            P[ms * 4 + r] = fmaf(acc[ms][j][r] + b2v[j],
                                 shPatch[pxb + r * PS], P[ms * 4 + r]);
        }
      }

      // reduce-scatter across the 16-lane column group (R6-proven):
      // final P[0] at lane = full column sum for px=(c15>>2)*16+quad*4+(c15&3)
      #pragma unroll
      for (int m = 8; m >= 1; m >>= 1) {
        const bool hi = (c15 & m) != 0;
        #pragma unroll
        for (int j = 0; j < m; ++j) {
          float keep = hi ? P[j + m] : P[j];
          float send = hi ? P[j] : P[j + m];
          float recv = __shfl_xor(send, m, 64);
          P[j] = keep + recv;
        }
      }
      oacc += P[0];
    }

    const int x = x0 + (c15 >> 2) * 16 + quad * 4 + (c15 & 3);
    out[((b * CO + o) * IMGH + y) * IMGW + x] = oacc;
  }
}

// ---------------------------------------------------------------------------
extern "C" void kernel_launch(void* const* d_in, const int* in_sizes, int n_in,
                              void* d_out, int out_size, void* d_ws, size_t ws_size,
                              hipStream_t stream) {
  const float* in  = (const float*)d_in[0];   // [4,16,128,128]
  const float* foa = (const float*)d_in[1];   // [4,2]
  const float* W1  = (const float*)d_in[2];   // [2,256]
  const float* b1  = (const float*)d_in[3];   // [256]
  const float* W2  = (const float*)d_in[4];   // [256,2304]
  const float* b2  = (const float*)d_in[5];   // [2304]
  float* out = (float*)d_out;
  short* W2b = (short*)d_ws;                  // 16*8*144*32 bf16 = 1.18 MB

  prep_w2<<<288, 256, 0, stream>>>(W2, W2b);
  ngconv_main<<<1024, 256, 0, stream>>>(in, foa, W1, b1, W2b, b2, out);
}

// Round 10
// 238.840 us; speedup vs baseline: 1.8618x; 1.0016x over previous
//
#include <hip/hip_runtime.h>

// Problem constants (fixed by reference)
#define CI    16
#define CO    16
#define HID   256
#define KPAD  288    // 256 + 32; k==256 row carries b2 (VALU-free bias), rest 0
#define NKK   9      // KPAD/32 MFMA K-steps
#define NCH   144    // CI*9 columns per output channel
#define IMGH  128
#define IMGW  128
#define PS    148    // shPatch row stride in floats (2-way-free epilogue reads)
#define KKSTR (NCH * 32)        // shorts per kk block  = 4608
#define OSTRS (NKK * NCH * 32)  // shorts per o         = 41472

typedef float f32x4  __attribute__((ext_vector_type(4)));
typedef short bf16x8 __attribute__((ext_vector_type(8)));

__device__ __host__ __forceinline__ short f2bf(float f) {
  union { float f; unsigned u; } c; c.f = f;
  unsigned b = c.u + 0x7FFFu + ((c.u >> 16) & 1u);   // RNE
  return (short)(b >> 16);
}

// ---------------------------------------------------------------------------
// Prep: W2 [256][2304] fp32 (+ b2[2304]) -> W2b [o][kk:9][n:144][k:32] bf16,
// K padded to 288 (row 256 = b2, rows 257..287 = 0).
// grid = 36 col-blocks * 9 kk = 324 blocks x 256 threads.
// ---------------------------------------------------------------------------
__global__ void prep_w2(const float* __restrict__ W2, const float* __restrict__ b2,
                        short* __restrict__ W2b) {
  __shared__ float tile[32][65];
  const int kk = blockIdx.x % NKK;
  const int colbase = (blockIdx.x / NKK) * 64;
  const int tid = threadIdx.x;

  for (int e = tid; e < 2048; e += 256) {
    int klr = e >> 6;          // 0..31
    int cc  = e & 63;
    int col = colbase + cc;
    float v;
    if (kk < 8) v = W2[(kk * 32 + klr) * (CO * NCH) + col];
    else        v = (klr == 0) ? b2[col] : 0.f;
    tile[klr][cc] = v;
  }
  __syncthreads();
  for (int e = tid; e < 2048; e += 256) {
    int cc = e >> 5;           // 0..63
    int kl = e & 31;
    int col = colbase + cc;
    int o = col / NCH;
    int n = col - o * NCH;
    W2b[(((o * NKK + kk) * NCH + n) << 5) + kl] = f2bf(tile[kl][cc]);
  }
}

// ---------------------------------------------------------------------------
// Main fused kernel, v10 = R8 structure (194 us, passed post-timing) +
//  (a) K=288 with b2 as K-row (removes epilogue bias VALU; R6-proven),
//  (b) copy-free 2-buffer ping-pong B prefetch, fully inline, NO arrays
//      passed by reference (R9's reference-taking body() is the prime
//      suspect for scratch demotion + graph-replay divergence).
// One block = 64 consecutive pixels of one image row. 4 waves; wave w
// computes channels {w, w+4, w+8, w+12}; M=64/wave, N=144/channel in
// 3 passes of 3 n-tiles (acc[4][3] = 48 regs, no spill; R8: VGPR=88).
// shHf in MFMA fragment order (conflict-free ds_read_b128);
// shPatch[px][n] stride 148 (exact 2-way = free).
// grid = 4 batches * 128 rows * 2 half-rows = 1024 blocks x 256 threads.
// ---------------------------------------------------------------------------
__global__ __launch_bounds__(256, 2)
void ngconv_main(const float* __restrict__ in, const float* __restrict__ foa,
                 const float* __restrict__ W1, const float* __restrict__ b1,
                 const short* __restrict__ W2b, float* __restrict__ out) {
  __shared__ short shHf[36 * 512];        // 36 frags (ms,kk) x 1 KiB = 36.9 KB
  __shared__ float shPatch[64 * PS];      // patch matrix, 37.9 KB

  const int tid  = threadIdx.x;
  const int lane = tid & 63;
  const int wv   = tid >> 6;
  const int c15  = lane & 15;
  const int quad = lane >> 4;

  const int blk = blockIdx.x;
  const int b   = blk >> 8;
  const int rem = blk & 255;
  const int y   = rem >> 1;
  const int x0  = (rem & 1) << 6;

  const float fx  = foa[b * 2 + 0];
  const float fy  = foa[b * 2 + 1];
  const float dyv = (float)y - fy;

  const int ry0 = (y == 0) ? 1 : (y - 1);
  const int ry2 = (y == IMGH - 1) ? (IMGH - 2) : (y + 1);

  // ---- shPatch[px][n]: patch value for pixel px (block-local), column n
  for (int e = tid; e < NCH * 64; e += 256) {
    int n  = e >> 6;                  // 0..143
    int px = e & 63;
    int i = n / 9, q = n - i * 9;
    int dyr = q / 3, dx = q - dyr * 3;
    int ryr = (dyr == 0) ? ry0 : ((dyr == 1) ? y : ry2);
    int x = x0 + px + dx - 1;
    x = (x < 0) ? 1 : ((x > IMGW - 1) ? (IMGW - 2) : x);   // reflect
    shPatch[px * PS + n] = in[((b * CI + i) * IMGH + ryr) * IMGW + x];
  }

  // ---- shHf: H in fragment order. frag(ms,kk) = A[16 px][32 k]; lane slot
  // (c15=px, quad=k-octet). 64 px x 36 k-slots = 2304 = 9 exact iterations.
  for (int g = tid; g < 64 * 36; g += 256) {
    int px = g & 63;
    int ks = g >> 6;                  // 0..35 -> k0 = ks*8
    int k0 = ks << 3;
    float dxv = (float)(x0 + px) - fx;
    short hv[8];
    if (k0 < HID) {
      #pragma unroll
      for (int j = 0; j < 8; ++j) {
        int k = k0 + j;
        float h = fmaxf(fmaf(dxv, W1[k], fmaf(dyv, W1[HID + k], b1[k])), 0.f);
        hv[j] = f2bf(h);
      }
    } else {
      #pragma unroll
      for (int j = 0; j < 8; ++j) hv[j] = (k0 + j == HID) ? f2bf(1.f) : (short)0;
    }
    int ms = px >> 4;
    int kk = k0 >> 5;
    int lslot = ((k0 & 31) >> 3) * 16 + (px & 15);   // quad*16 + c15
    *(bf16x8*)&shHf[((ms * NKK + kk) << 9) + (lslot << 3)] = *(bf16x8*)hv;
  }
  __syncthreads();

  // ---- main loop: 4 output channels per wave, N in three passes of 3
  #pragma unroll 1
  for (int oj = 0; oj < 4; ++oj) {
    const int o = wv + oj * 4;
    const short* Bo = W2b + o * OSTRS + (c15 << 5) + (quad << 3);
    float oacc = 0.f;

    #pragma unroll 1
    for (int pass = 0; pass < 3; ++pass) {
      const short* Bp = Bo + (pass * 3) * 512;   // first n-tile of this pass
      f32x4 acc[4][3];
      #pragma unroll
      for (int ms = 0; ms < 4; ++ms)
        #pragma unroll
        for (int j = 0; j < 3; ++j)
          acc[ms][j] = (f32x4){0.f, 0.f, 0.f, 0.f};

      // copy-free 2-buffer ping-pong, distance-1 prefetch, explicit tail.
      bf16x8 bE[3], bO[3];
      #pragma unroll
      for (int j = 0; j < 3; ++j) bE[j] = *(const bf16x8*)&Bp[j << 9];

      #pragma unroll 1
      for (int t = 0; t < 4; ++t) {
        const int kkE = 2 * t;            // even kk, uses bE
        #pragma unroll
        for (int j = 0; j < 3; ++j)       // prefetch odd kk into bO
          bO[j] = *(const bf16x8*)&Bp[(kkE + 1) * KKSTR + (j << 9)];
        {
          const short* hp = shHf + (kkE << 9) + (lane << 3);
          #pragma unroll
          for (int ms = 0; ms < 4; ++ms) {
            bf16x8 af = *(const bf16x8*)&hp[ms * (NKK << 9)];
            #pragma unroll
            for (int j = 0; j < 3; ++j)
              acc[ms][j] = __builtin_amdgcn_mfma_f32_16x16x32_bf16(
                  af, bE[j], acc[ms][j], 0, 0, 0);
          }
        }
        #pragma unroll
        for (int j = 0; j < 3; ++j)       // prefetch next even kk into bE
          bE[j] = *(const bf16x8*)&Bp[(kkE + 2) * KKSTR + (j << 9)];
        {
          const short* hp = shHf + ((kkE + 1) << 9) + (lane << 3);
          #pragma unroll
          for (int ms = 0; ms < 4; ++ms) {
            bf16x8 af = *(const bf16x8*)&hp[ms * (NKK << 9)];
            #pragma unroll
            for (int j = 0; j < 3; ++j)
              acc[ms][j] = __builtin_amdgcn_mfma_f32_16x16x32_bf16(
                  af, bO[j], acc[ms][j], 0, 0, 0);
          }
        }
      }
      {   // tail kk=8, already in bE
        const short* hp = shHf + (8 << 9) + (lane << 3);
        #pragma unroll
        for (int ms = 0; ms < 4; ++ms) {
          bf16x8 af = *(const bf16x8*)&hp[ms * (NKK << 9)];
          #pragma unroll
          for (int j = 0; j < 3; ++j)
            acc[ms][j] = __builtin_amdgcn_mfma_f32_16x16x32_bf16(
                af, bE[j], acc[ms][j], 0, 0, 0);
        }
      }

      // ---- per-pass epilogue: P = acc * patch (b2 already in acc via K-row)
      float P[16];
      #pragma unroll
      for (int t = 0; t < 16; ++t) P[t] = 0.f;
      #pragma unroll
      for (int j = 0; j < 3; ++j) {
        int n15 = ((pass * 3 + j) << 4) + c15;
        #pragma unroll
        for (int ms = 0; ms < 4; ++ms) {
          int pxb = (ms * 16 + quad * 4) * PS + n15;
          #pragma unroll
          for (int r = 0; r < 4; ++r)
            P[ms * 4 + r] = fmaf(acc[ms][j][r], shPatch[pxb + r * PS],
                                 P[ms * 4 + r]);
        }
      }

      // reduce-scatter across the 16-lane column group (R6-proven):
      // final P[0] at lane = column sum for px=(c15>>2)*16+quad*4+(c15&3)
      #pragma unroll
      for (int m = 8; m >= 1; m >>= 1) {
        const bool hi = (c15 & m) != 0;
        #pragma unroll
        for (int j = 0; j < m; ++j) {
          float keep = hi ? P[j + m] : P[j];
          float send = hi ? P[j] : P[j + m];
          float recv = __shfl_xor(send, m, 64);
          P[j] = keep + recv;
        }
      }
      oacc += P[0];
    }

    const int x = x0 + (c15 >> 2) * 16 + quad * 4 + (c15 & 3);
    out[((b * CO + o) * IMGH + y) * IMGW + x] = oacc;
  }
}

// ---------------------------------------------------------------------------
extern "C" void kernel_launch(void* const* d_in, const int* in_sizes, int n_in,
                              void* d_out, int out_size, void* d_ws, size_t ws_size,
                              hipStream_t stream) {
  const float* in  = (const float*)d_in[0];   // [4,16,128,128]
  const float* foa = (const float*)d_in[1];   // [4,2]
  const float* W1  = (const float*)d_in[2];   // [2,256]
  const float* b1  = (const float*)d_in[3];   // [256]
  const float* W2  = (const float*)d_in[4];   // [256,2304]
  const float* b2  = (const float*)d_in[5];   // [2304]
  float* out = (float*)d_out;
  short* W2b = (short*)d_ws;                  // 16*9*144*32 bf16 = 1.33 MB

  prep_w2<<<324, 256, 0, stream>>>(W2, b2, W2b);
  ngconv_main<<<1024, 256, 0, stream>>>(in, foa, W1, b1, W2b, out);
}

// Round 11
// 190.022 us; speedup vs baseline: 2.3402x; 1.2569x over previous
//
#include <hip/hip_runtime.h>

// Problem constants (fixed by reference)
#define CI    16
#define CO    16
#define HID   256
#define KPAD  288    // 256 + 32; k==256 row carries b2 (VALU-free bias), rest 0
#define NKK   9      // KPAD/32 MFMA K-steps
#define NCH   144    // CI*9 columns per output channel
#define IMGH  128
#define IMGW  128
#define PTS   66     // shPatchT row stride in floats ([n][px], even -> b64 aligned)
#define KKSTR (NCH * 32)        // shorts per kk block  = 4608
#define OSTRS (NKK * NCH * 32)  // shorts per o         = 41472

typedef float f32x4  __attribute__((ext_vector_type(4)));
typedef float f32x2  __attribute__((ext_vector_type(2)));
typedef short bf16x8 __attribute__((ext_vector_type(8)));

__device__ __host__ __forceinline__ short f2bf(float f) {
  union { float f; unsigned u; } c; c.f = f;
  unsigned b = c.u + 0x7FFFu + ((c.u >> 16) & 1u);   // RNE
  return (short)(b >> 16);
}

// ---------------------------------------------------------------------------
// Prep: W2 [256][2304] fp32 (+ b2[2304]) -> W2b [o][kk:9][n:144][k:32] bf16,
// K padded to 288 (row 256 = b2, rows 257..287 = 0).
// grid = 36 col-blocks * 9 kk = 324 blocks x 256 threads.
// ---------------------------------------------------------------------------
__global__ void prep_w2(const float* __restrict__ W2, const float* __restrict__ b2,
                        short* __restrict__ W2b) {
  __shared__ float tile[32][65];
  const int kk = blockIdx.x % NKK;
  const int colbase = (blockIdx.x / NKK) * 64;
  const int tid = threadIdx.x;

  for (int e = tid; e < 2048; e += 256) {
    int klr = e >> 6;          // 0..31
    int cc  = e & 63;
    int col = colbase + cc;
    float v;
    if (kk < 8) v = W2[(kk * 32 + klr) * (CO * NCH) + col];
    else        v = (klr == 0) ? b2[col] : 0.f;
    tile[klr][cc] = v;
  }
  __syncthreads();
  for (int e = tid; e < 2048; e += 256) {
    int cc = e >> 5;           // 0..63
    int kl = e & 31;
    int col = colbase + cc;
    int o = col / NCH;
    int n = col - o * NCH;
    W2b[(((o * NKK + kk) * NCH + n) << 5) + kl] = f2bf(tile[kl][cc]);
  }
}

// ---------------------------------------------------------------------------
// Main fused kernel, v11 = R10 (187 us) with three epilogue cuts:
//  (a) reduce-scatter tree hoisted out of the pass loop: P[16] accumulates
//      across passes, ONE tree per oj (12 trees -> 4). +16 live regs, fits.
//  (b) shPatchT transposed to [n][px] (stride 66, even -> 8B aligned): the
//      4 r-values per lane are adjacent -> ds_read_b64 pairs (576 scalar
//      reads -> 288 b64), half the issue slots + address VALU.
//  (c) float2 epilogue math (ext_vector) -> v_pk_fma_f32 candidates.
// One block = 64 px of one image row; 4 waves; wave w owns channels
// {w, w+4, w+8, w+12}; M=64/wave, N=144/channel in 3 passes of 3 n-tiles,
// K=288 (b2 as K-row). Copy-free 2-buffer ping-pong B prefetch (R10).
// shHf in MFMA fragment order (conflict-free ds_read_b128).
// grid = 4 batches * 128 rows * 2 half-rows = 1024 blocks x 256 threads.
// ---------------------------------------------------------------------------
__global__ __launch_bounds__(256, 2)
void ngconv_main(const float* __restrict__ in, const float* __restrict__ foa,
                 const float* __restrict__ W1, const float* __restrict__ b1,
                 const short* __restrict__ W2b, float* __restrict__ out) {
  __shared__ short shHf[36 * 512];        // 36 frags (ms,kk) x 1 KiB = 36.9 KB
  __shared__ float shPatchT[NCH * PTS];   // patch matrix [n][px], 38.0 KB

  const int tid  = threadIdx.x;
  const int lane = tid & 63;
  const int wv   = tid >> 6;
  const int c15  = lane & 15;
  const int quad = lane >> 4;

  const int blk = blockIdx.x;
  const int b   = blk >> 8;
  const int rem = blk & 255;
  const int y   = rem >> 1;
  const int x0  = (rem & 1) << 6;

  const float fx  = foa[b * 2 + 0];
  const float fy  = foa[b * 2 + 1];
  const float dyv = (float)y - fy;

  const int ry0 = (y == 0) ? 1 : (y - 1);
  const int ry2 = (y == IMGH - 1) ? (IMGH - 2) : (y + 1);

  // ---- shPatchT[n][px]: patch value for column n, pixel px (block-local)
  for (int e = tid; e < NCH * 64; e += 256) {
    int n  = e >> 6;                  // 0..143
    int px = e & 63;
    int i = n / 9, q = n - i * 9;
    int dyr = q / 3, dx = q - dyr * 3;
    int ryr = (dyr == 0) ? ry0 : ((dyr == 1) ? y : ry2);
    int x = x0 + px + dx - 1;
    x = (x < 0) ? 1 : ((x > IMGW - 1) ? (IMGW - 2) : x);   // reflect
    shPatchT[n * PTS + px] = in[((b * CI + i) * IMGH + ryr) * IMGW + x];
  }

  // ---- shHf: H in fragment order. frag(ms,kk) = A[16 px][32 k]; lane slot
  // (c15=px, quad=k-octet). 64 px x 36 k-slots = 2304 = 9 exact iterations.
  for (int g = tid; g < 64 * 36; g += 256) {
    int px = g & 63;
    int ks = g >> 6;                  // 0..35 -> k0 = ks*8
    int k0 = ks << 3;
    float dxv = (float)(x0 + px) - fx;
    short hv[8];
    if (k0 < HID) {
      #pragma unroll
      for (int j = 0; j < 8; ++j) {
        int k = k0 + j;
        float h = fmaxf(fmaf(dxv, W1[k], fmaf(dyv, W1[HID + k], b1[k])), 0.f);
        hv[j] = f2bf(h);
      }
    } else {
      #pragma unroll
      for (int j = 0; j < 8; ++j) hv[j] = (k0 + j == HID) ? f2bf(1.f) : (short)0;
    }
    int ms = px >> 4;
    int kk = k0 >> 5;
    int lslot = ((k0 & 31) >> 3) * 16 + (px & 15);   // quad*16 + c15
    *(bf16x8*)&shHf[((ms * NKK + kk) << 9) + (lslot << 3)] = *(bf16x8*)hv;
  }
  __syncthreads();

  // ---- main loop: 4 output channels per wave, N in three passes of 3
  #pragma unroll 1
  for (int oj = 0; oj < 4; ++oj) {
    const int o = wv + oj * 4;
    const short* Bo = W2b + o * OSTRS + (c15 << 5) + (quad << 3);

    // per-oj partial sums (accumulate across all 3 passes; tree at the end)
    f32x2 P2[8];
    #pragma unroll
    for (int t = 0; t < 8; ++t) P2[t] = (f32x2){0.f, 0.f};

    #pragma unroll 1
    for (int pass = 0; pass < 3; ++pass) {
      const short* Bp = Bo + (pass * 3) * 512;   // first n-tile of this pass
      f32x4 acc[4][3];
      #pragma unroll
      for (int ms = 0; ms < 4; ++ms)
        #pragma unroll
        for (int j = 0; j < 3; ++j)
          acc[ms][j] = (f32x4){0.f, 0.f, 0.f, 0.f};

      // copy-free 2-buffer ping-pong, distance-1 prefetch, explicit tail.
      bf16x8 bE[3], bO[3];
      #pragma unroll
      for (int j = 0; j < 3; ++j) bE[j] = *(const bf16x8*)&Bp[j << 9];

      #pragma unroll 1
      for (int t = 0; t < 4; ++t) {
        const int kkE = 2 * t;            // even kk, uses bE
        #pragma unroll
        for (int j = 0; j < 3; ++j)       // prefetch odd kk into bO
          bO[j] = *(const bf16x8*)&Bp[(kkE + 1) * KKSTR + (j << 9)];
        {
          const short* hp = shHf + (kkE << 9) + (lane << 3);
          #pragma unroll
          for (int ms = 0; ms < 4; ++ms) {
            bf16x8 af = *(const bf16x8*)&hp[ms * (NKK << 9)];
            #pragma unroll
            for (int j = 0; j < 3; ++j)
              acc[ms][j] = __builtin_amdgcn_mfma_f32_16x16x32_bf16(
                  af, bE[j], acc[ms][j], 0, 0, 0);
          }
        }
        #pragma unroll
        for (int j = 0; j < 3; ++j)       // prefetch next even kk into bE
          bE[j] = *(const bf16x8*)&Bp[(kkE + 2) * KKSTR + (j << 9)];
        {
          const short* hp = shHf + ((kkE + 1) << 9) + (lane << 3);
          #pragma unroll
          for (int ms = 0; ms < 4; ++ms) {
            bf16x8 af = *(const bf16x8*)&hp[ms * (NKK << 9)];
            #pragma unroll
            for (int j = 0; j < 3; ++j)
              acc[ms][j] = __builtin_amdgcn_mfma_f32_16x16x32_bf16(
                  af, bO[j], acc[ms][j], 0, 0, 0);
          }
        }
      }
      {   // tail kk=8, already in bE
        const short* hp = shHf + (8 << 9) + (lane << 3);
        #pragma unroll
        for (int ms = 0; ms < 4; ++ms) {
          bf16x8 af = *(const bf16x8*)&hp[ms * (NKK << 9)];
          #pragma unroll
          for (int j = 0; j < 3; ++j)
            acc[ms][j] = __builtin_amdgcn_mfma_f32_16x16x32_bf16(
                af, bE[j], acc[ms][j], 0, 0, 0);
        }
      }

      // ---- per-pass patch contraction into P2 (b2 already in acc via K-row)
      // lane needs px = ms*16 + quad*4 + r; [n][px] layout -> r adjacent.
      #pragma unroll
      for (int j = 0; j < 3; ++j) {
        int n15 = ((pass * 3 + j) << 4) + c15;
        const float* prow = &shPatchT[n15 * PTS + (quad << 2)];
        #pragma unroll
        for (int ms = 0; ms < 4; ++ms) {
          f32x2 p01 = *(const f32x2*)&prow[ms * 16];      // ds_read_b64
          f32x2 p23 = *(const f32x2*)&prow[ms * 16 + 2];  // ds_read_b64
          f32x2 a01 = {acc[ms][j][0], acc[ms][j][1]};
          f32x2 a23 = {acc[ms][j][2], acc[ms][j][3]};
          P2[ms * 2 + 0] += a01 * p01;                    // v_pk_fma_f32 cand.
          P2[ms * 2 + 1] += a23 * p23;
        }
      }
    }

    // ---- ONE reduce-scatter tree per oj (was per pass: 12 -> 4 trees).
    // final P[0] at lane = column sum for px=(c15>>2)*16+quad*4+(c15&3)
    float P[16];
    #pragma unroll
    for (int t = 0; t < 16; ++t) P[t] = P2[t >> 1][t & 1];
    #pragma unroll
    for (int m = 8; m >= 1; m >>= 1) {
      const bool hi = (c15 & m) != 0;
      #pragma unroll
      for (int j = 0; j < m; ++j) {
        float keep = hi ? P[j + m] : P[j];
        float send = hi ? P[j] : P[j + m];
        float recv = __shfl_xor(send, m, 64);
        P[j] = keep + recv;
      }
    }

    const int x = x0 + (c15 >> 2) * 16 + quad * 4 + (c15 & 3);
    out[((b * CO + o) * IMGH + y) * IMGW + x] = P[0];
  }
}

// ---------------------------------------------------------------------------
extern "C" void kernel_launch(void* const* d_in, const int* in_sizes, int n_in,
                              void* d_out, int out_size, void* d_ws, size_t ws_size,
                              hipStream_t stream) {
  const float* in  = (const float*)d_in[0];   // [4,16,128,128]
  const float* foa = (const float*)d_in[1];   // [4,2]
  const float* W1  = (const float*)d_in[2];   // [2,256]
  const float* b1  = (const float*)d_in[3];   // [256]
  const float* W2  = (const float*)d_in[4];   // [256,2304]
  const float* b2  = (const float*)d_in[5];   // [2304]
  float* out = (float*)d_out;
  short* W2b = (short*)d_ws;                  // 16*9*144*32 bf16 = 1.33 MB

  prep_w2<<<324, 256, 0, stream>>>(W2, b2, W2b);
  ngconv_main<<<1024, 256, 0, stream>>>(in, foa, W1, b1, W2b, out);
}

// Round 12
// 182.889 us; speedup vs baseline: 2.4314x; 1.0390x over previous
//
#include <hip/hip_runtime.h>

// Problem constants (fixed by reference)
#define CI    16
#define CO    16
#define HID   256
#define KPAD  288    // 256 + 32; k==256 row carries b2 (VALU-free bias), rest 0
#define NKK   9      // KPAD/32 MFMA K-steps (B side; W2b layout)
#define NKH   8      // kk frags held in LDS (kk=8 pad frag synthesized in regs)
#define NCH   144    // CI*9 columns per output channel
#define IMGH  128
#define IMGW  128
#define PTS   68     // shPatchT row stride in SHORTS (136 B: 8B-aligned, <=4-way)
#define KKSTR (NCH * 32)        // shorts per kk block  = 4608
#define OSTRS (NKK * NCH * 32)  // shorts per o         = 41472

typedef float f32x4  __attribute__((ext_vector_type(4)));
typedef float f32x2  __attribute__((ext_vector_type(2)));
typedef short bf16x8 __attribute__((ext_vector_type(8)));

__device__ __host__ __forceinline__ short f2bf(float f) {
  union { float f; unsigned u; } c; c.f = f;
  unsigned b = c.u + 0x7FFFu + ((c.u >> 16) & 1u);   // RNE
  return (short)(b >> 16);
}

// ---------------------------------------------------------------------------
// Prep: W2 [256][2304] fp32 (+ b2[2304]) -> W2b [o][kk:9][n:144][k:32] bf16,
// K padded to 288 (row 256 = b2, rows 257..287 = 0).
// grid = 36 col-blocks * 9 kk = 324 blocks x 256 threads.
// ---------------------------------------------------------------------------
__global__ void prep_w2(const float* __restrict__ W2, const float* __restrict__ b2,
                        short* __restrict__ W2b) {
  __shared__ float tile[32][65];
  const int kk = blockIdx.x % NKK;
  const int colbase = (blockIdx.x / NKK) * 64;
  const int tid = threadIdx.x;

  for (int e = tid; e < 2048; e += 256) {
    int klr = e >> 6;          // 0..31
    int cc  = e & 63;
    int col = colbase + cc;
    float v;
    if (kk < 8) v = W2[(kk * 32 + klr) * (CO * NCH) + col];
    else        v = (klr == 0) ? b2[col] : 0.f;
    tile[klr][cc] = v;
  }
  __syncthreads();
  for (int e = tid; e < 2048; e += 256) {
    int cc = e >> 5;           // 0..63
    int kl = e & 31;
    int col = colbase + cc;
    int o = col / NCH;
    int n = col - o * NCH;
    W2b[(((o * NKK + kk) * NCH + n) << 5) + kl] = f2bf(tile[kl][cc]);
  }
}

// ---------------------------------------------------------------------------
// Main fused kernel, v12 = R11 (146 us) + LDS diet for 3 blocks/CU:
//  (a) kk=8 pad fragment (constant: k=256 row = 1.0 for b2, rest 0) is
//      synthesized in 4 regs -> shHf holds kk=0..7 only (32.8 KB) and the
//      GEMM drops 48 ds_read_b128/wave.
//  (b) shPatchT stored bf16, stride 68 shorts (136 B: b64-aligned, <=4-way
//      conflicts): 19.6 KB, and ONE ds_read_b64 now delivers all 4 r-values
//      (epilogue DS reads halved); unpacked with 2 shifts per pair.
//  Total LDS 51.1 KB < 53.3 -> 3 blocks/CU = 12 waves (was 2/8).
// One block = 64 px of one image row; 4 waves; wave w owns channels
// {w, w+4, w+8, w+12}; M=64/wave, N=144/channel in 3 passes of 3 n-tiles,
// K=288 (b2 as K-row). Copy-free 2-buffer ping-pong B prefetch (R10).
// P[16] accumulates across passes; ONE reduce-scatter tree per oj (R11).
// grid = 4 batches * 128 rows * 2 half-rows = 1024 blocks x 256 threads.
// ---------------------------------------------------------------------------
__global__ __launch_bounds__(256, 3)
void ngconv_main(const float* __restrict__ in, const float* __restrict__ foa,
                 const float* __restrict__ W1, const float* __restrict__ b1,
                 const short* __restrict__ W2b, float* __restrict__ out) {
  __shared__ short shHf[32 * 512];        // 32 frags (ms,kk 0..7) = 32.8 KB
  __shared__ short shPatchT[NCH * PTS];   // patch matrix [n][px] bf16, 19.6 KB

  const int tid  = threadIdx.x;
  const int lane = tid & 63;
  const int wv   = tid >> 6;
  const int c15  = lane & 15;
  const int quad = lane >> 4;

  const int blk = blockIdx.x;
  const int b   = blk >> 8;
  const int rem = blk & 255;
  const int y   = rem >> 1;
  const int x0  = (rem & 1) << 6;

  const float fx  = foa[b * 2 + 0];
  const float fy  = foa[b * 2 + 1];
  const float dyv = (float)y - fy;

  const int ry0 = (y == 0) ? 1 : (y - 1);
  const int ry2 = (y == IMGH - 1) ? (IMGH - 2) : (y + 1);

  // ---- shPatchT[n][px] (bf16): patch value for column n, pixel px
  for (int e = tid; e < NCH * 64; e += 256) {
    int n  = e >> 6;                  // 0..143
    int px = e & 63;
    int i = n / 9, q = n - i * 9;
    int dyr = q / 3, dx = q - dyr * 3;
    int ryr = (dyr == 0) ? ry0 : ((dyr == 1) ? y : ry2);
    int x = x0 + px + dx - 1;
    x = (x < 0) ? 1 : ((x > IMGW - 1) ? (IMGW - 2) : x);   // reflect
    shPatchT[n * PTS + px] = f2bf(in[((b * CI + i) * IMGH + ryr) * IMGW + x]);
  }

  // ---- shHf: H in fragment order, kk=0..7 only. frag(ms,kk) = A[16px][32k];
  // lane slot (c15=px, quad=k-octet). 64 px x 32 k-slots = 2048 = 8 exact its.
  for (int g = tid; g < 64 * 32; g += 256) {
    int px = g & 63;
    int ks = g >> 6;                  // 0..31 -> k0 = ks*8 < 256
    int k0 = ks << 3;
    float dxv = (float)(x0 + px) - fx;
    short hv[8];
    #pragma unroll
    for (int j = 0; j < 8; ++j) {
      int k = k0 + j;
      float h = fmaxf(fmaf(dxv, W1[k], fmaf(dyv, W1[HID + k], b1[k])), 0.f);
      hv[j] = f2bf(h);
    }
    int ms = px >> 4;
    int kk = k0 >> 5;
    int lslot = ((k0 & 31) >> 3) * 16 + (px & 15);   // quad*16 + c15
    *(bf16x8*)&shHf[((ms * NKH + kk) << 9) + (lslot << 3)] = *(bf16x8*)hv;
  }

  // ---- kk=8 pad fragment, constant, in registers: k=256 -> 1.0 (b2 row)
  bf16x8 af8 = (bf16x8){0, 0, 0, 0, 0, 0, 0, 0};
  if (quad == 0) af8[0] = (short)0x3F80;   // bf16 1.0

  __syncthreads();

  // ---- main loop: 4 output channels per wave, N in three passes of 3
  #pragma unroll 1
  for (int oj = 0; oj < 4; ++oj) {
    const int o = wv + oj * 4;
    const short* Bo = W2b + o * OSTRS + (c15 << 5) + (quad << 3);

    // per-oj partial sums (accumulate across all 3 passes; tree at the end)
    f32x2 P2[8];
    #pragma unroll
    for (int t = 0; t < 8; ++t) P2[t] = (f32x2){0.f, 0.f};

    #pragma unroll 1
    for (int pass = 0; pass < 3; ++pass) {
      const short* Bp = Bo + (pass * 3) * 512;   // first n-tile of this pass
      f32x4 acc[4][3];
      #pragma unroll
      for (int ms = 0; ms < 4; ++ms)
        #pragma unroll
        for (int j = 0; j < 3; ++j)
          acc[ms][j] = (f32x4){0.f, 0.f, 0.f, 0.f};

      // copy-free 2-buffer ping-pong, distance-1 prefetch, explicit tail.
      bf16x8 bE[3], bO[3];
      #pragma unroll
      for (int j = 0; j < 3; ++j) bE[j] = *(const bf16x8*)&Bp[j << 9];

      #pragma unroll 1
      for (int t = 0; t < 4; ++t) {
        const int kkE = 2 * t;            // even kk, uses bE
        #pragma unroll
        for (int j = 0; j < 3; ++j)       // prefetch odd kk into bO
          bO[j] = *(const bf16x8*)&Bp[(kkE + 1) * KKSTR + (j << 9)];
        {
          const short* hp = shHf + (kkE << 9) + (lane << 3);
          #pragma unroll
          for (int ms = 0; ms < 4; ++ms) {
            bf16x8 af = *(const bf16x8*)&hp[ms * (NKH << 9)];
            #pragma unroll
            for (int j = 0; j < 3; ++j)
              acc[ms][j] = __builtin_amdgcn_mfma_f32_16x16x32_bf16(
                  af, bE[j], acc[ms][j], 0, 0, 0);
          }
        }
        #pragma unroll
        for (int j = 0; j < 3; ++j)       // prefetch next even kk into bE
          bE[j] = *(const bf16x8*)&Bp[(kkE + 2) * KKSTR + (j << 9)];
        {
          const short* hp = shHf + ((kkE + 1) << 9) + (lane << 3);
          #pragma unroll
          for (int ms = 0; ms < 4; ++ms) {
            bf16x8 af = *(const bf16x8*)&hp[ms * (NKH << 9)];
            #pragma unroll
            for (int j = 0; j < 3; ++j)
              acc[ms][j] = __builtin_amdgcn_mfma_f32_16x16x32_bf16(
                  af, bO[j], acc[ms][j], 0, 0, 0);
          }
        }
      }
      {   // tail kk=8 (b2 K-row): af8 from registers, B already in bE
        #pragma unroll
        for (int ms = 0; ms < 4; ++ms)
          #pragma unroll
          for (int j = 0; j < 3; ++j)
            acc[ms][j] = __builtin_amdgcn_mfma_f32_16x16x32_bf16(
                af8, bE[j], acc[ms][j], 0, 0, 0);
      }

      // ---- per-pass patch contraction into P2 (b2 already in acc).
      // lane needs px = ms*16 + quad*4 + r; [n][px] bf16 -> ONE b64 = 4 vals.
      #pragma unroll
      for (int j = 0; j < 3; ++j) {
        int n15 = ((pass * 3 + j) << 4) + c15;
        const short* prow = &shPatchT[n15 * PTS + (quad << 2)];
        #pragma unroll
        for (int ms = 0; ms < 4; ++ms) {
          uint2 u = *(const uint2*)&prow[ms * 16];        // ds_read_b64
          float p0 = __uint_as_float(u.x << 16);
          float p1 = __uint_as_float(u.x & 0xFFFF0000u);
          float p2 = __uint_as_float(u.y << 16);
          float p3 = __uint_as_float(u.y & 0xFFFF0000u);
          f32x2 a01 = {acc[ms][j][0], acc[ms][j][1]};
          f32x2 a23 = {acc[ms][j][2], acc[ms][j][3]};
          P2[ms * 2 + 0] += a01 * (f32x2){p0, p1};        // v_pk_fma_f32 cand.
          P2[ms * 2 + 1] += a23 * (f32x2){p2, p3};
        }
      }
    }

    // ---- ONE reduce-scatter tree per oj.
    // final P[0] at lane = column sum for px=(c15>>2)*16+quad*4+(c15&3)
    float P[16];
    #pragma unroll
    for (int t = 0; t < 16; ++t) P[t] = P2[t >> 1][t & 1];
    #pragma unroll
    for (int m = 8; m >= 1; m >>= 1) {
      const bool hi = (c15 & m) != 0;
      #pragma unroll
      for (int j = 0; j < m; ++j) {
        float keep = hi ? P[j + m] : P[j];
        float send = hi ? P[j] : P[j + m];
        float recv = __shfl_xor(send, m, 64);
        P[j] = keep + recv;
      }
    }

    const int x = x0 + (c15 >> 2) * 16 + quad * 4 + (c15 & 3);
    out[((b * CO + o) * IMGH + y) * IMGW + x] = P[0];
  }
}

// ---------------------------------------------------------------------------
extern "C" void kernel_launch(void* const* d_in, const int* in_sizes, int n_in,
                              void* d_out, int out_size, void* d_ws, size_t ws_size,
                              hipStream_t stream) {
  const float* in  = (const float*)d_in[0];   // [4,16,128,128]
  const float* foa = (const float*)d_in[1];   // [4,2]
  const float* W1  = (const float*)d_in[2];   // [2,256]
  const float* b1  = (const float*)d_in[3];   // [256]
  const float* W2  = (const float*)d_in[4];   // [256,2304]
  const float* b2  = (const float*)d_in[5];   // [2304]
  float* out = (float*)d_out;
  short* W2b = (short*)d_ws;                  // 16*9*144*32 bf16 = 1.33 MB

  prep_w2<<<324, 256, 0, stream>>>(W2, b2, W2b);
  ngconv_main<<<1024, 256, 0, stream>>>(in, foa, W1, b1, W2b, out);
}